// Round 1
// baseline (1245.905 us; speedup 1.0000x reference)
//
#include <hip/hip_runtime.h>
#include <hip/hip_bf16.h>

// Problem constants
#define GSZ 36
// x: (16,32,224,224) f32 ; w: (32,32,3,3) ; bias: (32,)
static const int NX = 16 * 32 * 224 * 224;   // 25,690,112
static const int NW = 32 * 32 * 3 * 3;       // 9,216
static const int GXN = (NX + GSZ - 1) / GSZ; // 713,615 (last group has 8 elems)
static const int GWN = NW / GSZ;             // 256 exactly

// e = floor(log2(m)) for normal m>0, via exponent field (exact).
// scale = 2^(e-7), inv = 2^(7-e) — both exact powers of two.
__device__ __forceinline__ void bfp_scales(float m, float& scale, float& inv) {
    int e = (int)((__float_as_uint(m) >> 23) & 0xffu) - 127;
    scale = __uint_as_float((unsigned)(e + 120) << 23);  // exp field e-7+127
    inv   = __uint_as_float((unsigned)(134 - e) << 23);  // exp field 7-e+127
}

// One thread per group of 36 consecutive flat elements. f32 in -> bf16 out.
// Quantized values have <=8 significant bits -> bf16 conversion is exact
// (upper-16-bit truncation suffices, no rounding needed).
__global__ void k_quant_bf16(const float* __restrict__ in,
                             __hip_bfloat16* __restrict__ out,
                             int n, int ngroups) {
    int g = blockIdx.x * blockDim.x + threadIdx.x;
    if (g >= ngroups) return;
    int base = g * GSZ;
    int cnt = n - base; if (cnt > GSZ) cnt = GSZ;
    float v[GSZ];
    if (cnt == GSZ) {
        const float4* p = reinterpret_cast<const float4*>(in + base); // 144B-aligned
        #pragma unroll
        for (int i = 0; i < 9; ++i) {
            float4 t = p[i];
            v[4*i+0] = t.x; v[4*i+1] = t.y; v[4*i+2] = t.z; v[4*i+3] = t.w;
        }
    } else {
        #pragma unroll
        for (int i = 0; i < GSZ; ++i) v[i] = 0.0f;
        for (int i = 0; i < cnt; ++i) v[i] = in[base + i];
    }
    float m = 0.0f;
    #pragma unroll
    for (int i = 0; i < GSZ; ++i) m = fmaxf(m, fabsf(v[i]));
    if (m > 0.0f) {
        float scale, inv; bfp_scales(m, scale, inv);
        #pragma unroll
        for (int i = 0; i < GSZ; ++i) v[i] = rintf(v[i] * inv) * scale;
    }
    if (cnt == GSZ) {
        // 36 bf16 = 9 x uint2 (8B) stores; byte offset 72g is 8-aligned
        uint2* q = reinterpret_cast<uint2*>(reinterpret_cast<unsigned short*>(out) + base);
        #pragma unroll
        for (int i = 0; i < 9; ++i) {
            uint2 t;
            t.x = (__float_as_uint(v[4*i+0]) >> 16) | (__float_as_uint(v[4*i+1]) & 0xffff0000u);
            t.y = (__float_as_uint(v[4*i+2]) >> 16) | (__float_as_uint(v[4*i+3]) & 0xffff0000u);
            q[i] = t;
        }
    } else {
        unsigned short* o = reinterpret_cast<unsigned short*>(out) + base;
        for (int i = 0; i < cnt; ++i) o[i] = (unsigned short)(__float_as_uint(v[i]) >> 16);
    }
}

// In-place BFP quantize of the f32 conv output.
__global__ void k_quant_f32_inplace(float* buf, int n, int ngroups) {
    int g = blockIdx.x * blockDim.x + threadIdx.x;
    if (g >= ngroups) return;
    int base = g * GSZ;
    int cnt = n - base; if (cnt > GSZ) cnt = GSZ;
    float v[GSZ];
    if (cnt == GSZ) {
        const float4* p = reinterpret_cast<const float4*>(buf + base);
        #pragma unroll
        for (int i = 0; i < 9; ++i) {
            float4 t = p[i];
            v[4*i+0] = t.x; v[4*i+1] = t.y; v[4*i+2] = t.z; v[4*i+3] = t.w;
        }
    } else {
        #pragma unroll
        for (int i = 0; i < GSZ; ++i) v[i] = 0.0f;
        for (int i = 0; i < cnt; ++i) v[i] = buf[base + i];
    }
    float m = 0.0f;
    #pragma unroll
    for (int i = 0; i < GSZ; ++i) m = fmaxf(m, fabsf(v[i]));
    if (m > 0.0f) {
        float scale, inv; bfp_scales(m, scale, inv);
        #pragma unroll
        for (int i = 0; i < GSZ; ++i) v[i] = rintf(v[i] * inv) * scale;
    }
    if (cnt == GSZ) {
        float4* q = reinterpret_cast<float4*>(buf + base);
        #pragma unroll
        for (int i = 0; i < 9; ++i)
            q[i] = make_float4(v[4*i+0], v[4*i+1], v[4*i+2], v[4*i+3]);
    } else {
        for (int i = 0; i < cnt; ++i) buf[base + i] = v[i];
    }
}

// Direct 3x3 SAME conv, fp32 accumulate from exact-bf16 quantized operands.
// Block: 256 threads -> 32(h) x 64(w) tile for one (b, co).
// Thread: 2x4 register tile (24 LDS reads per 72 FMAs).
#define TH 32
#define TW 64
#define HALO_H 34
#define HALO_W 66
#define XST 67   // LDS row stride (odd -> conflicts <= 4-way on reads)

__global__ __launch_bounds__(256) void k_conv(const __hip_bfloat16* __restrict__ xq,
                                              const __hip_bfloat16* __restrict__ wq,
                                              const float* __restrict__ bias,
                                              float* __restrict__ out) {
    __shared__ float xsm[HALO_H * XST];  // 2278 f32
    __shared__ float wsm[288];

    int tid = threadIdx.x;
    int bz  = blockIdx.z;          // b*32 + co
    int co  = bz & 31;
    int h0  = blockIdx.y * TH;
    int w0  = blockIdx.x * TW;
    int ty  = tid >> 4;            // 0..15 -> rows 2ty..2ty+1
    int tx  = tid & 15;            // 0..15 -> cols 4tx..4tx+3

    for (int i = tid; i < 288; i += 256)
        wsm[i] = __bfloat162float(wq[co * 288 + i]);

    float bsv = bias[co];
    float acc[2][4];
    #pragma unroll
    for (int r = 0; r < 2; ++r)
        #pragma unroll
        for (int j = 0; j < 4; ++j) acc[r][j] = bsv;

    const int HW = 224 * 224;
    const __hip_bfloat16* xbase = xq + (bz >> 5) * 32 * HW;  // b * 32 planes

    for (int ci = 0; ci < 32; ++ci) {
        __syncthreads();  // also covers wsm staging on first iteration
        const __hip_bfloat16* xp = xbase + ci * HW;
        for (int idx = tid; idx < HALO_H * HALO_W; idx += 256) {
            int r = idx / HALO_W;
            int c = idx - r * HALO_W;
            int gh = h0 + r - 1;
            int gw = w0 + c - 1;
            float val = 0.0f;
            if ((unsigned)gh < 224u && (unsigned)gw < 224u)
                val = __bfloat162float(xp[gh * 224 + gw]);
            xsm[r * XST + c] = val;
        }
        __syncthreads();

        float xv[4][6];
        #pragma unroll
        for (int r = 0; r < 4; ++r)
            #pragma unroll
            for (int c = 0; c < 6; ++c)
                xv[r][c] = xsm[(2 * ty + r) * XST + 4 * tx + c];

        const float* wp = &wsm[ci * 9];
        #pragma unroll
        for (int kh = 0; kh < 3; ++kh)
            #pragma unroll
            for (int kw = 0; kw < 3; ++kw) {
                float wv = wp[kh * 3 + kw];
                #pragma unroll
                for (int rr = 0; rr < 2; ++rr)
                    #pragma unroll
                    for (int j = 0; j < 4; ++j)
                        acc[rr][j] = fmaf(xv[rr + kh][kw + j], wv, acc[rr][j]);
            }
    }

    int w = w0 + 4 * tx;
    if (w < 224) {  // last w-tile (w0=192) masks tx>=8 cleanly at float4 granularity
        #pragma unroll
        for (int rr = 0; rr < 2; ++rr) {
            int h = h0 + 2 * ty + rr;
            *reinterpret_cast<float4*>(out + (bz * 224 + h) * 224 + w) =
                make_float4(acc[rr][0], acc[rr][1], acc[rr][2], acc[rr][3]);
        }
    }
}

extern "C" void kernel_launch(void* const* d_in, const int* in_sizes, int n_in,
                              void* d_out, int out_size, void* d_ws, size_t ws_size,
                              hipStream_t stream) {
    (void)in_sizes; (void)n_in; (void)out_size; (void)ws_size;
    const float* x    = (const float*)d_in[0];
    const float* w    = (const float*)d_in[1];
    const float* bias = (const float*)d_in[2];
    float* out        = (float*)d_out;

    // workspace: xq (25,690,112 bf16 = 51.4 MB), then wq (9216 bf16)
    __hip_bfloat16* xq = (__hip_bfloat16*)d_ws;
    __hip_bfloat16* wq = xq + NX;

    k_quant_bf16<<<(GXN + 255) / 256, 256, 0, stream>>>(x, xq, NX, GXN);
    k_quant_bf16<<<1, 256, 0, stream>>>(w, wq, NW, GWN);
    k_conv<<<dim3(4, 7, 16 * 32), 256, 0, stream>>>(xq, wq, bias, out);
    k_quant_f32_inplace<<<(GXN + 255) / 256, 256, 0, stream>>>(out, NX, GXN);
}

// Round 2
// 403.988 us; speedup vs baseline: 3.0840x; 3.0840x over previous
//
#include <hip/hip_runtime.h>
#include <hip/hip_bf16.h>
#include <string.h>

// Problem constants
#define GSZ 36
static const int NX = 16 * 32 * 224 * 224;   // 25,690,112
static const int NW = 32 * 32 * 3 * 3;       // 9,216
static const int GXN = (NX + GSZ - 1) / GSZ; // 713,615
static const int HWp = 224 * 224;            // 50,176

typedef short bf16x8 __attribute__((ext_vector_type(8)));
typedef float f32x4  __attribute__((ext_vector_type(4)));

// e = floor(log2(m)) for normal m>0 via exponent field (exact).
__device__ __forceinline__ void bfp_scales(float m, float& scale, float& inv) {
    int e = (int)((__float_as_uint(m) >> 23) & 0xffu) - 127;
    scale = __uint_as_float((unsigned)(e + 120) << 23);  // 2^(e-7)
    inv   = __uint_as_float((unsigned)(134 - e) << 23);  // 2^(7-e)
}

__device__ __forceinline__ unsigned short f2bf(float f) {
    return (unsigned short)(__float_as_uint(f) >> 16);   // exact for BFP-8 values
}

// ---------- quantize x: f32 NCHW -> bf16(raw ushort) NCHW ----------
__global__ void k_quant_bf16(const float* __restrict__ in,
                             unsigned short* __restrict__ out,
                             int n, int ngroups) {
    int g = blockIdx.x * blockDim.x + threadIdx.x;
    if (g >= ngroups) return;
    int base = g * GSZ;
    int cnt = n - base; if (cnt > GSZ) cnt = GSZ;
    float v[GSZ];
    if (cnt == GSZ) {
        const float4* p = reinterpret_cast<const float4*>(in + base);
        #pragma unroll
        for (int i = 0; i < 9; ++i) {
            float4 t = p[i];
            v[4*i+0] = t.x; v[4*i+1] = t.y; v[4*i+2] = t.z; v[4*i+3] = t.w;
        }
    } else {
        #pragma unroll
        for (int i = 0; i < GSZ; ++i) v[i] = 0.0f;
        for (int i = 0; i < cnt; ++i) v[i] = in[base + i];
    }
    float m = 0.0f;
    #pragma unroll
    for (int i = 0; i < GSZ; ++i) m = fmaxf(m, fabsf(v[i]));
    if (m > 0.0f) {
        float scale, inv; bfp_scales(m, scale, inv);
        #pragma unroll
        for (int i = 0; i < GSZ; ++i) v[i] = rintf(v[i] * inv) * scale;
    }
    if (cnt == GSZ) {
        uint2* q = reinterpret_cast<uint2*>(out + base);
        #pragma unroll
        for (int i = 0; i < 9; ++i) {
            uint2 t;
            t.x = (__float_as_uint(v[4*i+0]) >> 16) | (__float_as_uint(v[4*i+1]) & 0xffff0000u);
            t.y = (__float_as_uint(v[4*i+2]) >> 16) | (__float_as_uint(v[4*i+3]) & 0xffff0000u);
            q[i] = t;
        }
    } else {
        for (int i = 0; i < cnt; ++i) out[base + i] = f2bf(v[i]);
    }
}

// ---------- fallback: quantize x f32 NCHW -> bf16 NHWC directly (scatter) ----------
__global__ void k_quant_scatter(const float* __restrict__ in,
                                unsigned short* __restrict__ xt,
                                int n, int ngroups) {
    int g = blockIdx.x * blockDim.x + threadIdx.x;
    if (g >= ngroups) return;
    int base = g * GSZ;
    int cnt = n - base; if (cnt > GSZ) cnt = GSZ;
    float v[GSZ];
    if (cnt == GSZ) {
        const float4* p = reinterpret_cast<const float4*>(in + base);
        #pragma unroll
        for (int i = 0; i < 9; ++i) {
            float4 t = p[i];
            v[4*i+0] = t.x; v[4*i+1] = t.y; v[4*i+2] = t.z; v[4*i+3] = t.w;
        }
    } else {
        #pragma unroll
        for (int i = 0; i < GSZ; ++i) v[i] = 0.0f;
        for (int i = 0; i < cnt; ++i) v[i] = in[base + i];
    }
    float m = 0.0f;
    #pragma unroll
    for (int i = 0; i < GSZ; ++i) m = fmaxf(m, fabsf(v[i]));
    if (m > 0.0f) {
        float scale, inv; bfp_scales(m, scale, inv);
        #pragma unroll
        for (int i = 0; i < GSZ; ++i) v[i] = rintf(v[i] * inv) * scale;
    }
    int plane = base / HWp;
    int rem = base - plane * HWp;
    for (int i = 0; i < cnt; ++i) {
        xt[((size_t)(plane >> 5) * HWp + rem) * 32 + (plane & 31)] = f2bf(v[i]);
        if (++rem == HWp) { rem = 0; ++plane; }
    }
}

// ---------- transpose: bf16 NCHW -> bf16 NHWC ----------
__global__ __launch_bounds__(256) void k_nchw2nhwc(const unsigned short* __restrict__ xq,
                                                   unsigned short* __restrict__ xt) {
    __shared__ __align__(16) unsigned short ts[2 * 224 * 32];  // 28672 B
    int b = blockIdx.y;
    int h0 = blockIdx.x * 2;
    int t = threadIdx.x;
    int ci = t & 31, hh = (t >> 5) & 1, wb = t >> 6;          // wb 0..3
    const unsigned short* src = xq + ((size_t)(b * 32 + ci) * 224 + h0 + hh) * 224;
    #pragma unroll
    for (int k = 0; k < 7; ++k) {
        int wch = wb + 4 * k;                                  // 0..27
        union { uint4 v4; unsigned short u[8]; } u;
        u.v4 = *reinterpret_cast<const uint4*>(src + wch * 8);
        #pragma unroll
        for (int i = 0; i < 8; ++i)
            ts[(hh * 224 + wch * 8 + i) * 32 + ci] = u.u[i];
    }
    __syncthreads();
    unsigned short* dst = xt + ((size_t)b * HWp + h0 * 224) * 32;
    #pragma unroll
    for (int k = 0; k < 7; ++k) {
        int q = t + k * 256;                                   // 0..1791
        *reinterpret_cast<uint4*>(dst + q * 8) = *reinterpret_cast<const uint4*>(&ts[q * 8]);
    }
}

// ---------- quantize w + layout to wt[s][co][ci] bf16 ----------
__global__ void k_quant_wt(const float* __restrict__ w, unsigned short* __restrict__ wt) {
    int g = threadIdx.x;            // 1 block, 256 threads = 256 groups exactly
    int base = g * GSZ;
    float v[GSZ];
    const float4* p = reinterpret_cast<const float4*>(w + base);
    #pragma unroll
    for (int i = 0; i < 9; ++i) {
        float4 t = p[i];
        v[4*i+0] = t.x; v[4*i+1] = t.y; v[4*i+2] = t.z; v[4*i+3] = t.w;
    }
    float m = 0.0f;
    #pragma unroll
    for (int i = 0; i < GSZ; ++i) m = fmaxf(m, fabsf(v[i]));
    if (m > 0.0f) {
        float scale, inv; bfp_scales(m, scale, inv);
        #pragma unroll
        for (int i = 0; i < GSZ; ++i) v[i] = rintf(v[i] * inv) * scale;
    }
    #pragma unroll
    for (int i = 0; i < GSZ; ++i) {
        int f = base + i;
        int co = f / 288, rem = f - co * 288;
        int ci = rem / 9, s = rem - ci * 9;
        wt[s * 1024 + co * 32 + ci] = f2bf(v[i]);
    }
}

// ---------- MFMA conv: 3x3 SAME as 9 shifted K=32 GEMMs ----------
// Block: 256 thr (4 waves), tile 16h x 32w x 32co for one b. NHWC bf16 in.
// LDS halo: 18 rows x 34 px, pixel stride 40 shorts (80 B: 16B-aligned, ~2-way banks).
#define PXS 40
__global__ __launch_bounds__(256, 2) void k_conv_mfma(const unsigned short* __restrict__ xt,
                                                      const unsigned short* __restrict__ wt,
                                                      const float* __restrict__ bias,
                                                      float* __restrict__ out) {
    __shared__ __align__(16) unsigned short xs[18 * 34 * PXS];  // 48960 B

    int tid  = threadIdx.x;
    int lane = tid & 63;
    int wid  = tid >> 6;
    int b  = blockIdx.z;
    int h0 = blockIdx.y * 16;
    int w0 = blockIdx.x * 32;

    // --- stage 18x34 halo (all 32 ci) from NHWC global ---
    const unsigned short* xb = xt + (size_t)b * HWp * 32;
    #pragma unroll
    for (int k = 0; k < 10; ++k) {
        int q = tid + k * 256;
        if (q < 2448) {                       // 18*34*4 16B-chunks
            int r = q / 136;
            int rem = q - r * 136;
            int p = rem >> 2, ch = rem & 3;
            int gh = h0 + r - 1, gw = w0 + p - 1;
            uint4 val = make_uint4(0u, 0u, 0u, 0u);
            if ((unsigned)gh < 224u && (unsigned)gw < 224u)
                val = *reinterpret_cast<const uint4*>(xb + ((size_t)(gh * 224 + gw)) * 32 + ch * 8);
            *reinterpret_cast<uint4*>(&xs[(r * 34 + p) * PXS + ch * 8]) = val;
        }
    }

    // --- B fragments: wt[s][co][ci], lane n=lane&15 (co), k=(lane>>4)*8+j (ci) ---
    bf16x8 Bf[9][2];
    #pragma unroll
    for (int s = 0; s < 9; ++s)
        #pragma unroll
        for (int hf = 0; hf < 2; ++hf)
            Bf[s][hf] = *reinterpret_cast<const bf16x8*>(
                wt + s * 1024 + (hf * 16 + (lane & 15)) * 32 + (lane >> 4) * 8);

    // --- acc init = bias (conv+bias then quantize) ---
    float b0 = bias[lane & 15];
    float b1 = bias[16 + (lane & 15)];
    f32x4 acc[8][2];
    #pragma unroll
    for (int g = 0; g < 8; ++g) {
        acc[g][0] = (f32x4){b0, b0, b0, b0};
        acc[g][1] = (f32x4){b1, b1, b1, b1};
    }

    __syncthreads();

    // --- 9 shifts x 8 px-groups x 2 co-halves = 144 MFMAs/wave ---
    int row4 = wid << 2;
    int kchunk = (lane >> 4) << 3;            // A k-offset in shorts
    #pragma unroll
    for (int s = 0; s < 9; ++s) {
        int kh = s / 3, kw = s - kh * 3;
        #pragma unroll
        for (int g = 0; g < 8; ++g) {
            int row = row4 + (g >> 1);
            int col = ((g & 1) << 4) + (lane & 15);
            bf16x8 A = *reinterpret_cast<const bf16x8*>(
                &xs[((row + kh) * 34 + col + kw) * PXS + kchunk]);
            acc[g][0] = __builtin_amdgcn_mfma_f32_16x16x32_bf16(A, Bf[s][0], acc[g][0], 0, 0, 0);
            acc[g][1] = __builtin_amdgcn_mfma_f32_16x16x32_bf16(A, Bf[s][1], acc[g][1], 0, 0, 0);
        }
    }

    // --- epilogue: C col=lane&15=co, row=(lane>>4)*4+reg=px -> float4 over w ---
    int co_l = lane & 15;
    int m0 = (lane >> 4) << 2;
    #pragma unroll
    for (int g = 0; g < 8; ++g) {
        int row = row4 + (g >> 1);
        int wcol = w0 + ((g & 1) << 4) + m0;
        int h = h0 + row;
        #pragma unroll
        for (int hf = 0; hf < 2; ++hf) {
            int co = (hf << 4) + co_l;
            f32x4 v = acc[g][hf];
            *reinterpret_cast<float4*>(out + ((size_t)(b * 32 + co)) * HWp + h * 224 + wcol) =
                make_float4(v[0], v[1], v[2], v[3]);
        }
    }
}

// ---------- in-place BFP quantize of f32 conv output ----------
__global__ void k_quant_f32_inplace(float* buf, int n, int ngroups) {
    int g = blockIdx.x * blockDim.x + threadIdx.x;
    if (g >= ngroups) return;
    int base = g * GSZ;
    int cnt = n - base; if (cnt > GSZ) cnt = GSZ;
    float v[GSZ];
    if (cnt == GSZ) {
        const float4* p = reinterpret_cast<const float4*>(buf + base);
        #pragma unroll
        for (int i = 0; i < 9; ++i) {
            float4 t = p[i];
            v[4*i+0] = t.x; v[4*i+1] = t.y; v[4*i+2] = t.z; v[4*i+3] = t.w;
        }
    } else {
        #pragma unroll
        for (int i = 0; i < GSZ; ++i) v[i] = 0.0f;
        for (int i = 0; i < cnt; ++i) v[i] = buf[base + i];
    }
    float m = 0.0f;
    #pragma unroll
    for (int i = 0; i < GSZ; ++i) m = fmaxf(m, fabsf(v[i]));
    if (m > 0.0f) {
        float scale, inv; bfp_scales(m, scale, inv);
        #pragma unroll
        for (int i = 0; i < GSZ; ++i) v[i] = rintf(v[i] * inv) * scale;
    }
    if (cnt == GSZ) {
        float4* q = reinterpret_cast<float4*>(buf + base);
        #pragma unroll
        for (int i = 0; i < 9; ++i)
            q[i] = make_float4(v[4*i+0], v[4*i+1], v[4*i+2], v[4*i+3]);
    } else {
        for (int i = 0; i < cnt; ++i) buf[base + i] = v[i];
    }
}

extern "C" void kernel_launch(void* const* d_in, const int* in_sizes, int n_in,
                              void* d_out, int out_size, void* d_ws, size_t ws_size,
                              hipStream_t stream) {
    (void)in_sizes; (void)n_in; (void)out_size;
    const float* x    = (const float*)d_in[0];
    const float* w    = (const float*)d_in[1];
    const float* bias = (const float*)d_in[2];
    float* out        = (float*)d_out;

    // ws layout: [xt: NX bf16][wt: 9216 bf16][xq: NX bf16 (path A only)]
    unsigned short* xt = (unsigned short*)d_ws;
    unsigned short* wt = xt + NX;
    unsigned short* xq = wt + NW;
    size_t need_two_buf = ((size_t)2 * NX + NW) * 2;

    k_quant_wt<<<1, 256, 0, stream>>>(w, wt);

    if (ws_size >= need_two_buf) {
        // Path A: quantize NCHW then tiled transpose to NHWC (coalesced)
        k_quant_bf16<<<(GXN + 255) / 256, 256, 0, stream>>>(x, xq, NX, GXN);
        k_nchw2nhwc<<<dim3(112, 16), 256, 0, stream>>>(xq, xt);
    } else {
        // Path B: fused quantize + NHWC scatter (fits round-1 footprint)
        k_quant_scatter<<<(GXN + 255) / 256, 256, 0, stream>>>(x, xt, NX, GXN);
    }

    k_conv_mfma<<<dim3(7, 14, 16), 256, 0, stream>>>(xt, wt, bias, out);
    k_quant_f32_inplace<<<(GXN + 255) / 256, 256, 0, stream>>>(out, NX, GXN);
}

// Round 4
// 262.613 us; speedup vs baseline: 4.7443x; 1.5383x over previous
//
#include <hip/hip_runtime.h>
#include <hip/hip_bf16.h>

#define GSZ 36
static const int NX  = 16 * 32 * 224 * 224;     // 25,690,112
static const int NX4 = NX / 4;                  // 6,422,528 (NX % 4 == 0)
static const int NW  = 32 * 32 * 3 * 3;         // 9,216
static const int GXN = (NX + GSZ - 1) / GSZ;    // 713,615
static const int HWp = 224 * 224;               // 50,176

typedef short bf16x8 __attribute__((ext_vector_type(8)));
typedef float f32x4  __attribute__((ext_vector_type(4)));

// floor(n/36), exact for n < 2^31
__device__ __forceinline__ unsigned div36(unsigned n) {
    return (unsigned)(((unsigned long long)n * 954437177ull) >> 35);
}
// scale = 2^(floor(log2 m) - 7) via exponent field (m normal > 0)
__device__ __forceinline__ float scale_from_max(float m) {
    int e = (int)((__float_as_uint(m) >> 23) & 0xffu) - 127;
    return __uint_as_float((unsigned)(e + 120) << 23);
}
// 1/scale for power-of-two scale: bits = 0x7F000000 - scale_bits
__device__ __forceinline__ float inv_from_scale(float s) {
    return __uint_as_float(0x7F000000u - __float_as_uint(s));
}
__device__ __forceinline__ unsigned short f2bf(float f) {
    return (unsigned short)(__float_as_uint(f) >> 16);  // exact for BFP-8 values
}

// ---------- quantize w + layout to wt[s][co][ci] bf16 ----------
__global__ void k_quant_wt(const float* __restrict__ w, unsigned short* __restrict__ wt) {
    int g = threadIdx.x;            // 1 block, 256 threads = 256 groups exactly
    int base = g * GSZ;
    float v[GSZ];
    const float4* p = reinterpret_cast<const float4*>(w + base);
    #pragma unroll
    for (int i = 0; i < 9; ++i) {
        float4 t = p[i];
        v[4*i+0] = t.x; v[4*i+1] = t.y; v[4*i+2] = t.z; v[4*i+3] = t.w;
    }
    float m = 0.0f;
    #pragma unroll
    for (int i = 0; i < GSZ; ++i) m = fmaxf(m, fabsf(v[i]));
    if (m > 0.0f) {
        float s = scale_from_max(m), inv = inv_from_scale(s);
        #pragma unroll
        for (int i = 0; i < GSZ; ++i) v[i] = rintf(v[i] * inv) * s;
    }
    #pragma unroll
    for (int i = 0; i < GSZ; ++i) {
        int f = base + i;
        int co = f / 288, rem = f - co * 288;
        int ci = rem / 9, s = rem - ci * 9;
        wt[s * 1024 + co * 32 + ci] = f2bf(v[i]);
    }
}

// ---------- fused x: BFP-quantize (flat-36 groups) + NCHW->NHWC, one pass ----------
// Block: (b, 2-row pair). Per ci the tile is one contiguous flat span [F, F+448).
// Groups straddle tile edges -> phase A scans the group-aligned cover [A, A+504)
// computing per-group maxabs via LDS atomicMax (uint order == f32 order for >=0).
#define TSTR 452   // bf16 tile row stride (bank-spread, keeps uint2 writes 8B-aligned)
__global__ __launch_bounds__(256, 4) void k_quant_x_fused(const float* __restrict__ x,
                                                          unsigned short* __restrict__ xt) {
    __shared__ unsigned short tile[32 * TSTR];   // 28,928 B quantized bf16 tile
    __shared__ float scl[32 * 14];               // max-bits during A, scales after
    __shared__ int rem36s[32], offs[32];

    int t = threadIdx.x;
    int b = blockIdx.y, hp = blockIdx.x;
    int F0 = (b * 32) * HWp + hp * 448;

    if (t < 32) {
        int F = F0 + t * HWp;
        int r = F - 36 * (int)div36((unsigned)F);  // F % 36
        rem36s[t] = r;
        offs[t] = (F - r) & 3;                     // always 0 (36k % 4 == 0); kept for safety
    }
    // BUGFIX (round 3): 448 > blockDim -> must stride, not `if (t < 448)`
    for (int i = t; i < 448; i += 256) ((unsigned*)scl)[i] = 0u;
    __syncthreads();

    // Phase A: group maxabs over the aligned cover [base4, base4+512) per ci
    for (int j = 0; j < 16; ++j) {
        int idx = t + 256 * j;                     // 4096 float4 chunks
        int ci = idx >> 7, c4 = idx & 127;
        int off = offs[ci];
        int base4 = F0 + ci * HWp - rem36s[ci] - off;   // group-aligned start
        int f4 = (base4 >> 2) + c4;
        float4 v = make_float4(0.f, 0.f, 0.f, 0.f);
        if ((unsigned)f4 < (unsigned)NX4)
            v = reinterpret_cast<const float4*>(x)[f4];
        int rel0 = 4 * c4 - off;                   // offset of v.x from A
        int r0c = rel0 > 0 ? rel0 : 0;
        int gia = (int)div36((unsigned)r0c);
        int bnd = 36 * gia + 36;
        float av[4] = {fabsf(v.x), fabsf(v.y), fabsf(v.z), fabsf(v.w)};
        float ma = 0.f, mb = 0.f;
        #pragma unroll
        for (int k = 0; k < 4; ++k) {
            int rel = rel0 + k;
            float a = ((unsigned)rel < 504u) ? av[k] : 0.f;  // 14 groups max
            if (rel < bnd) ma = fmaxf(ma, a); else mb = fmaxf(mb, a);
        }
        if (ma > 0.f) atomicMax((unsigned*)&scl[ci * 14 + gia], __float_as_uint(ma));
        if (mb > 0.f) atomicMax((unsigned*)&scl[ci * 14 + gia + 1], __float_as_uint(mb));
    }
    __syncthreads();
    // BUGFIX (round 3): stride over all 448 scale slots
    for (int i = t; i < 448; i += 256)
        scl[i] = scale_from_max(__uint_as_float(((unsigned*)scl)[i]));
    __syncthreads();

    // Phase C: re-read tile (L2-hot), quantize, pack bf16 into LDS
    for (int j = 0; j < 14; ++j) {
        int eidx = t + 256 * j;                    // 3584 float4 chunks of the tile
        int ci = ((eidx >> 4) * 293) >> 11;        // /112 (exact for eidx < 3584)
        int c4 = eidx - ci * 112;
        float4 v = reinterpret_cast<const float4*>(x)[((F0 + ci * HWp) >> 2) + c4];
        int rbase = rem36s[ci] + 4 * c4;           // offset from A
        int gi0 = (int)div36((unsigned)rbase);
        int rr = rbase - 36 * gi0;
        float vv[4] = {v.x, v.y, v.z, v.w};
        unsigned short qb[4];
        #pragma unroll
        for (int k = 0; k < 4; ++k) {
            int gi = gi0 + ((rr + k) >= 36 ? 1 : 0);
            float s = scl[ci * 14 + gi];
            qb[k] = f2bf(rintf(vv[k] * inv_from_scale(s)) * s);
        }
        uint2 o;
        o.x = (unsigned)qb[0] | ((unsigned)qb[1] << 16);
        o.y = (unsigned)qb[2] | ((unsigned)qb[3] << 16);
        *reinterpret_cast<uint2*>(&tile[ci * TSTR + 4 * c4]) = o;
    }
    __syncthreads();

    // Phase D: gather 8 ci per pixel, coalesced 16B NHWC stores
    unsigned short* ob = xt + ((size_t)b * HWp + hp * 448) * 32;
    for (int j = 0; j < 7; ++j) {
        int qd = t + 256 * j;                      // 1792 16B-chunks
        int px = qd >> 2;
        int c0 = (qd & 3) * 8;
        unsigned uu[4];
        #pragma unroll
        for (int p = 0; p < 4; ++p) {
            unsigned short lo = tile[(c0 + 2 * p) * TSTR + px];
            unsigned short hi = tile[(c0 + 2 * p + 1) * TSTR + px];
            uu[p] = (unsigned)lo | ((unsigned)hi << 16);
        }
        *reinterpret_cast<uint4*>(ob + (size_t)px * 32 + c0) =
            make_uint4(uu[0], uu[1], uu[2], uu[3]);
    }
}

// ---------- MFMA conv: 3x3 SAME as 9 shifted K=32 GEMMs, coalesced epilogue ----------
// mfma(A=w_frag[m=co], B=x_frag[n=px]) -> D row=co, col=px. Each scalar f32
// store instruction covers 4 x 64B full segments (lanes 0..15 = consecutive px).
#define PXS 40
__global__ __launch_bounds__(256, 2) void k_conv_mfma(const unsigned short* __restrict__ xt,
                                                      const unsigned short* __restrict__ wt,
                                                      const float* __restrict__ bias,
                                                      float* __restrict__ out) {
    __shared__ __align__(16) unsigned short xs[18 * 34 * PXS];  // 48,960 B

    int tid  = threadIdx.x;
    int lane = tid & 63;
    int wid  = tid >> 6;
    int b  = blockIdx.z;
    int h0 = blockIdx.y * 16;
    int w0 = blockIdx.x * 32;

    // stage 18x34 halo (all 32 ci) from NHWC
    const unsigned short* xb = xt + (size_t)b * HWp * 32;
    #pragma unroll
    for (int k = 0; k < 10; ++k) {
        int q = tid + k * 256;
        if (q < 2448) {                       // 18*34*4 16B-chunks
            int r = q / 136;
            int rem = q - r * 136;
            int p = rem >> 2, ch = rem & 3;
            int gh = h0 + r - 1, gw = w0 + p - 1;
            uint4 val = make_uint4(0u, 0u, 0u, 0u);
            if ((unsigned)gh < 224u && (unsigned)gw < 224u)
                val = *reinterpret_cast<const uint4*>(xb + ((size_t)(gh * 224 + gw)) * 32 + ch * 8);
            *reinterpret_cast<uint4*>(&xs[(r * 34 + p) * PXS + ch * 8]) = val;
        }
    }

    // weight fragments (A-operand: m=lane&15=co, k=(lane>>4)*8+j=ci)
    bf16x8 Wf[9][2];
    #pragma unroll
    for (int s = 0; s < 9; ++s)
        #pragma unroll
        for (int hf = 0; hf < 2; ++hf)
            Wf[s][hf] = *reinterpret_cast<const bf16x8*>(
                wt + s * 1024 + (hf * 16 + (lane & 15)) * 32 + (lane >> 4) * 8);

    // acc init = bias; D row = co = (lane>>4)*4 + reg (+16*hf)
    int m4 = (lane >> 4) << 2;
    f32x4 acc[8][2];
    {
        f32x4 b0, b1;
        #pragma unroll
        for (int r = 0; r < 4; ++r) {
            b0[r] = bias[m4 + r];
            b1[r] = bias[16 + m4 + r];
        }
        #pragma unroll
        for (int g = 0; g < 8; ++g) { acc[g][0] = b0; acc[g][1] = b1; }
    }

    __syncthreads();

    int row4 = wid << 2;
    int kchunk = (lane >> 4) << 3;
    #pragma unroll
    for (int s = 0; s < 9; ++s) {
        int kh = s / 3, kw = s - kh * 3;
        #pragma unroll
        for (int g = 0; g < 8; ++g) {
            int row = row4 + (g >> 1);
            int col = ((g & 1) << 4) + (lane & 15);
            bf16x8 X = *reinterpret_cast<const bf16x8*>(
                &xs[((row + kh) * 34 + col + kw) * PXS + kchunk]);
            acc[g][0] = __builtin_amdgcn_mfma_f32_16x16x32_bf16(Wf[s][0], X, acc[g][0], 0, 0, 0);
            acc[g][1] = __builtin_amdgcn_mfma_f32_16x16x32_bf16(Wf[s][1], X, acc[g][1], 0, 0, 0);
        }
    }

    // epilogue: col = lane&15 = px, row = m4 + reg = co -> line-coalesced stores
    int pxl = lane & 15;
    #pragma unroll
    for (int g = 0; g < 8; ++g) {
        int h = h0 + row4 + (g >> 1);
        int wl = w0 + ((g & 1) << 4) + pxl;
        size_t base = (size_t)(b * 32) * HWp + h * 224 + wl;
        #pragma unroll
        for (int hf = 0; hf < 2; ++hf)
            #pragma unroll
            for (int r = 0; r < 4; ++r)
                out[base + (size_t)((hf << 4) + m4 + r) * HWp] = acc[g][hf][r];
    }
}

// ---------- out-quant, in place, wave-cooperative (coalesced 16B ld/st) ----------
__global__ __launch_bounds__(256, 4) void k_quant_out(float* __restrict__ buf) {
    __shared__ float lds[4 * 2304];              // 36,864 B (wave: 64 groups = 2304 f32)
    int t = threadIdx.x, lane = t & 63, wid = t >> 6;
    int gbase = (blockIdx.x * 4 + wid) * 64;
    int f4base = gbase * 9;                      // gbase*36/4

    #pragma unroll
    for (int i = 0; i < 9; ++i) {
        int f4 = f4base + i * 64 + lane;
        float4 v = make_float4(0.f, 0.f, 0.f, 0.f);
        if ((unsigned)f4 < (unsigned)NX4) v = reinterpret_cast<const float4*>(buf)[f4];
        *reinterpret_cast<float4*>(&lds[wid * 2304 + (i * 64 + lane) * 4]) = v;
    }
    __syncthreads();

    if (gbase + lane < GXN) {
        float* p = &lds[wid * 2304 + lane * 36];    // byte 144*lane: 16B-aligned
        f32x4 vv[9];
        #pragma unroll
        for (int i = 0; i < 9; ++i) vv[i] = *reinterpret_cast<f32x4*>(p + 4 * i);
        float m = 0.f;
        #pragma unroll
        for (int i = 0; i < 9; ++i)
            #pragma unroll
            for (int k = 0; k < 4; ++k) m = fmaxf(m, fabsf(vv[i][k]));
        if (m > 0.f) {                               // guard: all-zero group stays zero
            float s = scale_from_max(m), inv = inv_from_scale(s);
            #pragma unroll
            for (int i = 0; i < 9; ++i) {
                #pragma unroll
                for (int k = 0; k < 4; ++k) vv[i][k] = rintf(vv[i][k] * inv) * s;
                *reinterpret_cast<f32x4*>(p + 4 * i) = vv[i];
            }
        }
    }
    __syncthreads();

    #pragma unroll
    for (int i = 0; i < 9; ++i) {
        int f4 = f4base + i * 64 + lane;
        if ((unsigned)f4 < (unsigned)NX4)
            reinterpret_cast<float4*>(buf)[f4] =
                *reinterpret_cast<float4*>(&lds[wid * 2304 + (i * 64 + lane) * 4]);
    }
}

extern "C" void kernel_launch(void* const* d_in, const int* in_sizes, int n_in,
                              void* d_out, int out_size, void* d_ws, size_t ws_size,
                              hipStream_t stream) {
    (void)in_sizes; (void)n_in; (void)out_size; (void)ws_size;
    const float* x    = (const float*)d_in[0];
    const float* w    = (const float*)d_in[1];
    const float* bias = (const float*)d_in[2];
    float* out        = (float*)d_out;

    unsigned short* xt = (unsigned short*)d_ws;   // NX bf16 NHWC (51.4 MB)
    unsigned short* wt = xt + NX;                 // 9,216 bf16

    k_quant_wt<<<1, 256, 0, stream>>>(w, wt);
    k_quant_x_fused<<<dim3(112, 16), 256, 0, stream>>>(x, xt);
    k_conv_mfma<<<dim3(7, 14, 16), 256, 0, stream>>>(xt, wt, bias, out);
    // 2788 blocks: ceil(ceil(713615/64)/4)
    k_quant_out<<<2788, 256, 0, stream>>>(out);
}